// Round 11
// baseline (472.409 us; speedup 1.0000x reference)
//
#include <hip/hip_runtime.h>
#include <math.h>

#define Bn 16
#define Cn 256
#define Ln 16384
#define Mn 64
#define LN_EPS 1e-5f
#define CHUNK 32
#define NCH (Ln / CHUNK)   // 512
#define XSTR 33            // LDS row stride: 33%32==1 -> <=2-way bank aliasing (free)

typedef float v4f __attribute__((ext_vector_type(4)));

// K1: fused logits + chunk softmax + pooling; the block that finishes the last
// chunk of a batch runs the ctx-combine + MLP epilogue for that batch inline
// (threadfence-reduction pattern). grid (NCH, Bn) = 8192 blocks, 256 thr,
// ~36 KB LDS -> 4 blocks/CU.
__global__ __launch_bounds__(256) void k_pool_fused(
        const float* __restrict__ x, const float* __restrict__ w_mask,
        const float* __restrict__ b_mask,
        float* __restrict__ ctxU,   // [Bn][NCH][Cn]
        float* __restrict__ mz,     // [Bn][NCH][2]
        const float* __restrict__ w1, const float* __restrict__ b1,
        const float* __restrict__ ln_g, const float* __restrict__ ln_b,
        const float* __restrict__ w2, const float* __restrict__ b2,
        float* __restrict__ add, int* __restrict__ cnt) {
    const int ch = blockIdx.x, b = blockIdx.y;
    const int t = threadIdx.x;   // 256
    __shared__ float xs[Cn * XSTR];     // 33792 B (reused as epilogue scratch)
    __shared__ float wm_s[Cn];
    __shared__ float red2[8 * CHUNK];
    __shared__ float e_s[CHUNK];
    __shared__ int last_s;

    wm_s[t] = w_mask[t];

    // ---- stage: x[b][c][ch*32 .. +32) -> xs[c][l]; 8 float4 loads/thread ----
    const size_t xbase = (size_t)b * Cn * Ln + (size_t)ch * CHUNK;
    const int c0 = t >> 3;        // 0..31
    const int f4 = t & 7;         // l = 4*f4
    #pragma unroll
    for (int r = 0; r < 8; ++r) {
        const int c = r * 32 + c0;
        float4 v = *(const float4*)(x + xbase + (size_t)c * Ln + 4 * f4);
        float* dst = xs + c * XSTR + 4 * f4;
        dst[0] = v.x; dst[1] = v.y; dst[2] = v.z; dst[3] = v.w;
    }
    __syncthreads();

    // ---- phase A: logits from LDS; half-wave hw covers 32 channels ----
    const int hw = t >> 5, lA = t & 31;
    {
        float p = 0.f;
        #pragma unroll 8
        for (int k = 0; k < 32; ++k) {
            const int c = hw * 32 + k;
            p += xs[c * XSTR + lA] * wm_s[c];
        }
        red2[hw * CHUNK + lA] = p;
    }
    __syncthreads();
    if (t < CHUNK) {
        float logit = b_mask[0];
        #pragma unroll
        for (int j = 0; j < 8; ++j) logit += red2[j * CHUNK + t];
        float m = logit;
        for (int off = 16; off; off >>= 1) m = fmaxf(m, __shfl_xor(m, off, 32));
        const float e = expf(logit - m);
        e_s[t] = e;
        float z = e;
        for (int off = 16; off; off >>= 1) z += __shfl_xor(z, off, 32);
        if (t == 0) {
            mz[(b * NCH + ch) * 2 + 0] = m;
            mz[(b * NCH + ch) * 2 + 1] = z;
        }
    }
    __syncthreads();

    // ---- phase B: thread t = channel; e_s[l] broadcast; no cross-lane reduce ----
    float acc = 0.f;
    #pragma unroll 8
    for (int l = 0; l < CHUNK; ++l)
        acc += xs[t * XSTR + l] * e_s[l];
    ctxU[((size_t)b * NCH + ch) * Cn + t] = acc;

    // ---- last-block-done ticket for batch b ----
    __syncthreads();
    if (t == 0) {
        __threadfence();                       // release our ctxU/mz writes
        last_s = (atomicAdd(&cnt[b], 1) == NCH - 1);
    }
    __syncthreads();
    if (!last_s) return;
    if (t == 0) __threadfence();               // acquire side before reading peers
    __syncthreads();

    // ================= epilogue for batch b (one block) =================
    // LDS overlay on xs (dead): sc_s[512] | ctx_s[256] | h_s[64] | red8[8]
    float* sc_s  = xs;
    float* ctx_s = xs + 512;
    float* h_s   = xs + 768;
    float* red8  = xs + 832;

    // scales: global M, Z over 512 chunks (thread t owns chunks t and t+256)
    const float m0 = mz[(b * NCH + t) * 2],       z0 = mz[(b * NCH + t) * 2 + 1];
    const float m1 = mz[(b * NCH + 256 + t) * 2], z1 = mz[(b * NCH + 256 + t) * 2 + 1];
    float m = fmaxf(m0, m1);
    for (int off = 32; off; off >>= 1) m = fmaxf(m, __shfl_xor(m, off, 64));
    if ((t & 63) == 0) red8[t >> 6] = m;
    __syncthreads();
    const float M = fmaxf(fmaxf(red8[0], red8[1]), fmaxf(red8[2], red8[3]));
    float zw = z0 * expf(m0 - M) + z1 * expf(m1 - M);
    for (int off = 32; off; off >>= 1) zw += __shfl_xor(zw, off, 64);
    if ((t & 63) == 0) red8[4 + (t >> 6)] = zw;
    __syncthreads();
    const float Z = red8[4] + red8[5] + red8[6] + red8[7];
    sc_s[t]       = expf(m0 - M) / Z;
    sc_s[256 + t] = expf(m1 - M) / Z;
    __syncthreads();

    // ctx[c] = sum_ch ctxU[b][ch][c] * sc[ch]   (c = t, coalesced per ch)
    {
        float s = 0.f;
        #pragma unroll 8
        for (int chk = 0; chk < NCH; ++chk)
            s += ctxU[((size_t)b * NCH + chk) * Cn + t] * sc_s[chk];
        ctx_s[t] = s;
    }
    __syncthreads();

    // MLP: h = relu(LN(w1 @ ctx + b1)); add = w2 @ h + b2
    const int m4 = t >> 2, j = t & 3;
    float hp = 0.f;
    for (int c = j; c < Cn; c += 4) hp += ctx_s[c] * w1[m4 * Cn + c];
    hp += __shfl_xor(hp, 1, 64);
    hp += __shfl_xor(hp, 2, 64);
    if (j == 0) h_s[m4] = hp + b1[m4];
    __syncthreads();

    if (t < 64) {
        float h = h_s[t];
        float mu = h;
        for (int off = 32; off; off >>= 1) mu += __shfl_xor(mu, off, 64);
        mu *= (1.f / 64.f);
        const float d = h - mu;
        float var = d * d;
        for (int off = 32; off; off >>= 1) var += __shfl_xor(var, off, 64);
        var *= (1.f / 64.f);
        h = d * rsqrtf(var + LN_EPS) * ln_g[t] + ln_b[t];
        h_s[t] = fmaxf(h, 0.f);
    }
    __syncthreads();

    float a = b2[t];
    #pragma unroll
    for (int mm = 0; mm < Mn; ++mm) a += h_s[mm] * w2[t * Mn + mm];
    add[b * Cn + t] = a;
}

// K2: out = x + add broadcast. Nontemporal stores. grid (4, Bn*Cn), 256 thr.
// (kernel boundary provides device-wide visibility of add[])
__global__ void k_out(const float* __restrict__ x, const float* __restrict__ add,
                      float* __restrict__ out) {
    const int bc = blockIdx.y;
    const float a = add[bc];
    const size_t base = (size_t)bc * Ln + (size_t)blockIdx.x * 4096;
    const float4* xi = (const float4*)(x + base);
    v4f* xo = (v4f*)(out + base);
    const int t = threadIdx.x;
    #pragma unroll
    for (int k = 0; k < 4; ++k) {
        float4 v = xi[k * 256 + t];
        v4f o = {v.x + a, v.y + a, v.z + a, v.w + a};
        __builtin_nontemporal_store(o, xo + k * 256 + t);
    }
}

extern "C" void kernel_launch(void* const* d_in, const int* in_sizes, int n_in,
                              void* d_out, int out_size, void* d_ws, size_t ws_size,
                              hipStream_t stream) {
    const float* x      = (const float*)d_in[0];
    const float* w_mask = (const float*)d_in[1];
    const float* b_mask = (const float*)d_in[2];
    const float* w1     = (const float*)d_in[3];
    const float* b1     = (const float*)d_in[4];
    const float* ln_g   = (const float*)d_in[5];
    const float* ln_b   = (const float*)d_in[6];
    const float* w2     = (const float*)d_in[7];
    const float* b2     = (const float*)d_in[8];
    float* out = (float*)d_out;

    float* ws   = (float*)d_ws;
    float* ctxU = ws;                                  // Bn*NCH*Cn = 2M floats (8 MiB)
    float* mz   = ctxU + (size_t)Bn * NCH * Cn;        // Bn*NCH*2 = 16384 floats
    float* add  = mz + (size_t)Bn * NCH * 2;           // Bn*Cn = 4096 floats
    int*   cnt  = (int*)(add + (size_t)Bn * Cn);       // Bn ints

    hipMemsetAsync(cnt, 0, Bn * sizeof(int), stream);
    k_pool_fused<<<dim3(NCH, Bn), 256, 0, stream>>>(x, w_mask, b_mask, ctxU, mz,
                                                    w1, b1, ln_g, ln_b, w2, b2,
                                                    add, cnt);
    k_out<<<dim3(4, Bn * Cn), 256, 0, stream>>>(x, add, out);
}

// Round 12
// 141.668 us; speedup vs baseline: 3.3346x; 3.3346x over previous
//
#include <hip/hip_runtime.h>
#include <math.h>

#define Bn 16
#define Cn 256
#define Ln 16384
#define Mn 64
#define LN_EPS 1e-5f
#define CHUNK 32
#define NCH (Ln / CHUNK)   // 512
#define XSTR 33            // LDS row stride: 33%32==1 -> <=2-way bank aliasing (free)

typedef float v4f __attribute__((ext_vector_type(4)));

// K1: fused logits + chunk softmax + pooling. Logit partials computed in
// registers DURING staging (no phase-A LDS pass, 2 syncs instead of 3).
// grid (NCH, Bn) = 8192 blocks, 256 thr, ~38 KB LDS -> 4 blocks/CU.
__global__ __launch_bounds__(256) void k_pool(
        const float* __restrict__ x, const float* __restrict__ w_mask,
        const float* __restrict__ b_mask,
        float* __restrict__ ctxU,   // [Bn][NCH][Cn]
        float* __restrict__ mz) {   // [Bn][NCH][2]
    const int ch = blockIdx.x, b = blockIdx.y;
    const int t = threadIdx.x;   // 256
    __shared__ float xs[Cn * XSTR];     // 33792 B
    __shared__ float redA[32 * 32];     // [c0][l] logit partials, 4 KB
    __shared__ float e_s[CHUNK];

    const size_t xbase = (size_t)b * Cn * Ln + (size_t)ch * CHUNK;
    const int c0 = t >> 3;        // 0..31: channel-group (owns channels r*32+c0)
    const int f4 = t & 7;         // l-quad (l = 4*f4)

    // per-thread mask weights (broadcast across the 8 threads sharing c0 -> L1)
    float wm_r[8];
    #pragma unroll
    for (int r = 0; r < 8; ++r) wm_r[r] = w_mask[r * 32 + c0];

    // ---- stage + register logit partials ----
    float4 p = {0.f, 0.f, 0.f, 0.f};
    #pragma unroll
    for (int r = 0; r < 8; ++r) {
        const int c = r * 32 + c0;
        float4 v = *(const float4*)(x + xbase + (size_t)c * Ln + 4 * f4);
        float* dst = xs + c * XSTR + 4 * f4;
        dst[0] = v.x; dst[1] = v.y; dst[2] = v.z; dst[3] = v.w;
        const float w = wm_r[r];
        p.x += v.x * w; p.y += v.y * w; p.z += v.z * w; p.w += v.w * w;
    }
    *(float4*)&redA[c0 * 32 + 4 * f4] = p;    // addr = 4t: conflict-free
    __syncthreads();

    // ---- finalize 32 logits + chunk softmax (lanes 0..31 of wave 0) ----
    if (t < CHUNK) {
        float logit = b_mask[0];
        #pragma unroll 8
        for (int i = 0; i < 32; ++i) logit += redA[i * 32 + t];
        float m = logit;
        for (int off = 16; off; off >>= 1) m = fmaxf(m, __shfl_xor(m, off, 32));
        const float e = expf(logit - m);
        e_s[t] = e;
        float z = e;
        for (int off = 16; off; off >>= 1) z += __shfl_xor(z, off, 32);
        if (t == 0) {
            mz[(b * NCH + ch) * 2 + 0] = m;
            mz[(b * NCH + ch) * 2 + 1] = z;
        }
    }
    __syncthreads();

    // ---- phase B: thread t = channel; e_s[l] broadcast; no cross-lane reduce ----
    float acc = 0.f;
    #pragma unroll 8
    for (int l = 0; l < CHUNK; ++l)
        acc += xs[t * XSTR + l] * e_s[l];
    ctxU[((size_t)b * NCH + ch) * Cn + t] = acc;
}

// K2: ctx[b][c] = sum_ch ctxU[b][ch][c] * exp(m_ch - M)/Z. grid (16, Bn), 256 thr.
__global__ void k_ctx(const float* __restrict__ ctxU, const float* __restrict__ mz,
                      float* __restrict__ ctx) {
    const int cblk = blockIdx.x, b = blockIdx.y;
    const int t = threadIdx.x;   // 256
    __shared__ float sc_s[NCH];
    __shared__ float red8[8];
    __shared__ float red[256];

    const float m0 = mz[(b * NCH + t) * 2],       z0 = mz[(b * NCH + t) * 2 + 1];
    const float m1 = mz[(b * NCH + 256 + t) * 2], z1 = mz[(b * NCH + 256 + t) * 2 + 1];
    float m = fmaxf(m0, m1);
    for (int off = 32; off; off >>= 1) m = fmaxf(m, __shfl_xor(m, off, 64));
    if ((t & 63) == 0) red8[t >> 6] = m;
    __syncthreads();
    const float M = fmaxf(fmaxf(red8[0], red8[1]), fmaxf(red8[2], red8[3]));
    float zw = z0 * expf(m0 - M) + z1 * expf(m1 - M);
    for (int off = 32; off; off >>= 1) zw += __shfl_xor(zw, off, 64);
    if ((t & 63) == 0) red8[4 + (t >> 6)] = zw;
    __syncthreads();
    const float Z = red8[4] + red8[5] + red8[6] + red8[7];
    sc_s[t]       = expf(m0 - M) / Z;
    sc_s[256 + t] = expf(m1 - M) / Z;
    __syncthreads();

    const int cl = t & 15, chl = t >> 4;
    const int c = cblk * 16 + cl;
    float p = 0.f;
    #pragma unroll 8
    for (int j = 0; j < 32; ++j) {
        const int chk = j * 16 + chl;
        p += ctxU[((size_t)b * NCH + chk) * Cn + c] * sc_s[chk];
    }
    red[chl * 16 + cl] = p;
    __syncthreads();
    if (t < 16) {
        float s = 0.f;
        #pragma unroll
        for (int j = 0; j < 16; ++j) s += red[j * 16 + t];
        ctx[b * Cn + cblk * 16 + t] = s;
    }
}

// K3: tiny MLP on normalized ctx. grid Bn, 256 thr.
__global__ void k_mlp(const float* __restrict__ ctx, const float* __restrict__ w1,
                      const float* __restrict__ b1, const float* __restrict__ ln_g,
                      const float* __restrict__ ln_b, const float* __restrict__ w2,
                      const float* __restrict__ b2, float* __restrict__ add) {
    const int b = blockIdx.x;
    const int t = threadIdx.x;   // 256
    __shared__ float ctx_s[Cn];
    __shared__ float h_s[Mn];
    ctx_s[t] = ctx[b * Cn + t];
    __syncthreads();

    const int m4 = t >> 2, j = t & 3;
    float hp = 0.f;
    for (int c = j; c < Cn; c += 4) hp += ctx_s[c] * w1[m4 * Cn + c];
    hp += __shfl_xor(hp, 1, 64);
    hp += __shfl_xor(hp, 2, 64);
    if (j == 0) h_s[m4] = hp + b1[m4];
    __syncthreads();

    if (t < 64) {
        float h = h_s[t];
        float mu = h;
        for (int off = 32; off; off >>= 1) mu += __shfl_xor(mu, off, 64);
        mu *= (1.f / 64.f);
        const float d = h - mu;
        float var = d * d;
        for (int off = 32; off; off >>= 1) var += __shfl_xor(var, off, 64);
        var *= (1.f / 64.f);
        h = d * rsqrtf(var + LN_EPS) * ln_g[t] + ln_b[t];
        h_s[t] = fmaxf(h, 0.f);
    }
    __syncthreads();

    float a = b2[t];
    #pragma unroll
    for (int mm = 0; mm < Mn; ++mm) a += h_s[mm] * w2[t * Mn + mm];
    add[b * Cn + t] = a;
}

// K4: out = x + add broadcast. Nontemporal stores. grid (4, Bn*Cn), 256 thr.
__global__ void k_out(const float* __restrict__ x, const float* __restrict__ add,
                      float* __restrict__ out) {
    const int bc = blockIdx.y;
    const float a = add[bc];
    const size_t base = (size_t)bc * Ln + (size_t)blockIdx.x * 4096;
    const float4* xi = (const float4*)(x + base);
    v4f* xo = (v4f*)(out + base);
    const int t = threadIdx.x;
    #pragma unroll
    for (int k = 0; k < 4; ++k) {
        float4 v = xi[k * 256 + t];
        v4f o = {v.x + a, v.y + a, v.z + a, v.w + a};
        __builtin_nontemporal_store(o, xo + k * 256 + t);
    }
}

extern "C" void kernel_launch(void* const* d_in, const int* in_sizes, int n_in,
                              void* d_out, int out_size, void* d_ws, size_t ws_size,
                              hipStream_t stream) {
    const float* x      = (const float*)d_in[0];
    const float* w_mask = (const float*)d_in[1];
    const float* b_mask = (const float*)d_in[2];
    const float* w1     = (const float*)d_in[3];
    const float* b1     = (const float*)d_in[4];
    const float* ln_g   = (const float*)d_in[5];
    const float* ln_b   = (const float*)d_in[6];
    const float* w2     = (const float*)d_in[7];
    const float* b2     = (const float*)d_in[8];
    float* out = (float*)d_out;

    float* ws   = (float*)d_ws;
    float* ctxU = ws;                                  // Bn*NCH*Cn = 2M floats (8 MiB)
    float* mz   = ctxU + (size_t)Bn * NCH * Cn;        // Bn*NCH*2 = 16384 floats
    float* ctx  = mz + (size_t)Bn * NCH * 2;           // Bn*Cn = 4096 floats
    float* add  = ctx + (size_t)Bn * Cn;               // Bn*Cn = 4096 floats

    k_pool<<<dim3(NCH, Bn), 256, 0, stream>>>(x, w_mask, b_mask, ctxU, mz);
    k_ctx<<<dim3(Cn / 16, Bn), 256, 0, stream>>>(ctxU, mz, ctx);
    k_mlp<<<Bn, 256, 0, stream>>>(ctx, w1, b1, ln_g, ln_b, w2, b2, add);
    k_out<<<dim3(4, Bn * Cn), 256, 0, stream>>>(x, add, out);
}